// Round 4
// baseline (963.160 us; speedup 1.0000x reference)
//
#include <hip/hip_runtime.h>
#include <hip/hip_bf16.h>

// Problem constants (fixed by reference)
#define T_STEPS 256
#define BATCH   16
#define HID     512
#define VOCAB   32000
#define M_TOT   (T_STEPS * BATCH)   // 4096
#define NT_DEC  250                 // 32000/128
#define KT_DEC  16                  // 512/32

typedef __attribute__((ext_vector_type(8))) short s8v;   // 8 bf16 (4 VGPRs)
typedef __attribute__((ext_vector_type(4))) float f4v;   // 4 f32 accum
typedef unsigned short ushort_t;

__device__ __forceinline__ unsigned short f2bf_rne(float f) {
  unsigned u = __float_as_uint(f);
  unsigned r = u + 0x7fffu + ((u >> 16) & 1u);
  return (unsigned short)(r >> 16);
}
__device__ __forceinline__ float bf2f(unsigned short s) {
  return __uint_as_float(((unsigned)s) << 16);
}
// Tile unit layout: tile = [128 rows r][4 k-groups kg] of s8v (16B) units.
// Physical unit index (bank-conflict-free for b128 frag reads: per 16-lane
// group, all 8 bank-quads hit exactly 2x):
__device__ __forceinline__ int unit_swz(int r, int kg) {
  return r * 4 + (kg ^ ((r >> 1) & 3));
}
// async global->LDS, 16B per lane; LDS dest = wave-uniform base + lane*16
__device__ __forceinline__ void gload16(const void* g, void* l) {
  __builtin_amdgcn_global_load_lds(
      (const __attribute__((address_space(1))) unsigned int*)g,
      (__attribute__((address_space(3))) unsigned int*)l, 16, 0, 0);
}

// ---------------------------------------------------------------------------
// K1 "head": blocks 0..127  = pre-GEMM (pre[m][i] = b1[i] + emb[tok[m]]@wx.T)
//            blocks 128..4127 = dec_w presplit -> tile-ready bf16 hi/lo images
// (merged so the presplit cost overlaps pre-GEMM instead of adding serial time)
// ---------------------------------------------------------------------------
__global__ __launch_bounds__(256, 2) void head_kernel(
    const int* __restrict__ tok, const float* __restrict__ emb,
    const float* __restrict__ w1, const float* __restrict__ b1f,
    float* __restrict__ pre,
    const float* __restrict__ dec_w, ushort_t* __restrict__ bhi,
    ushort_t* __restrict__ blo, int do_split) {
  if (blockIdx.x >= 128) {
    // ---- presplit role: one (nt, ks) 128x32 tile per block, 2 units/thread
    if (!do_split) return;
    const int pid = blockIdx.x - 128;
    const int nt = pid >> 4, ks = pid & 15;
    const int tid = threadIdx.x;
#pragma unroll
    for (int h = 0; h < 2; ++h) {
      int us = h * 256 + tid;              // source-order unit: r*4+kg
      int r = us >> 2, kg = us & 3;
      const float* src = dec_w + (size_t)(nt * 128 + r) * HID + ks * 32 + kg * 8;
      float4 v0 = *(const float4*)src;
      float4 v1 = *(const float4*)(src + 4);
      float av[8] = {v0.x, v0.y, v0.z, v0.w, v1.x, v1.y, v1.z, v1.w};
      s8v hi, lo;
#pragma unroll
      for (int j = 0; j < 8; ++j) {
        unsigned short hh = f2bf_rne(av[j]);
        hi[j] = (short)hh;
        lo[j] = (short)f2bf_rne(av[j] - bf2f(hh));
      }
      size_t base = ((size_t)(nt * 16 + ks) * 512 + unit_swz(r, kg)) * 8;
      *(s8v*)(bhi + base) = hi;
      *(s8v*)(blo + base) = lo;
    }
    return;
  }
  // ---- pre-GEMM role (unchanged math from rounds 1-3)
  __shared__ s8v Ah[512], Al[512], Bh[512], Bl[512];
  const int mt = blockIdx.x & 31, nt = blockIdx.x >> 5;
  const int tid = threadIdx.x;
  const int lane = tid & 63, wave = tid >> 6;
  const int wm = wave >> 1, wn = wave & 1;
  const int m0 = mt * 128, n0 = nt * 128;
  f4v acc[4][4] = {};

  for (int ks = 0; ks < 16; ++ks) {
    const int k0 = ks * 32;
#pragma unroll
    for (int c = 0; c < 2; ++c) {
      int idx = c * 256 + tid;
      int r = idx >> 2, kg = idx & 3;
      int kgp = kg ^ (r & 3);
      int t_ = tok[m0 + r];
      const float* as = emb + (size_t)t_ * HID + k0 + kg * 8;
      float4 a0 = *(const float4*)as;
      float4 a1 = *(const float4*)(as + 4);
      float av[8] = {a0.x, a0.y, a0.z, a0.w, a1.x, a1.y, a1.z, a1.w};
      s8v ah, al;
#pragma unroll
      for (int j = 0; j < 8; ++j) {
        unsigned short h = f2bf_rne(av[j]);
        ah[j] = (short)h;
        al[j] = (short)f2bf_rne(av[j] - bf2f(h));
      }
      Ah[r * 4 + kgp] = ah;  Al[r * 4 + kgp] = al;
      const float* bs = w1 + (size_t)(n0 + r) * 1024 + k0 + kg * 8;
      float4 b0 = *(const float4*)bs;
      float4 b1v = *(const float4*)(bs + 4);
      float bv[8] = {b0.x, b0.y, b0.z, b0.w, b1v.x, b1v.y, b1v.z, b1v.w};
      s8v bh, bl;
#pragma unroll
      for (int j = 0; j < 8; ++j) {
        unsigned short h = f2bf_rne(bv[j]);
        bh[j] = (short)h;
        bl[j] = (short)f2bf_rne(bv[j] - bf2f(h));
      }
      Bh[r * 4 + kgp] = bh;  Bl[r * 4 + kgp] = bl;
    }
    __syncthreads();
    s8v afh[4], afl[4], bfh[4], bfl[4];
#pragma unroll
    for (int f = 0; f < 4; ++f) {
      int rA = wm * 64 + f * 16 + (lane & 15);
      afh[f] = Ah[rA * 4 + ((lane >> 4) ^ (rA & 3))];
      afl[f] = Al[rA * 4 + ((lane >> 4) ^ (rA & 3))];
      int rB = wn * 64 + f * 16 + (lane & 15);
      bfh[f] = Bh[rB * 4 + ((lane >> 4) ^ (rB & 3))];
      bfl[f] = Bl[rB * 4 + ((lane >> 4) ^ (rB & 3))];
    }
#pragma unroll
    for (int i = 0; i < 4; ++i)
#pragma unroll
      for (int j = 0; j < 4; ++j) {
        acc[i][j] = __builtin_amdgcn_mfma_f32_16x16x32_bf16(afh[i], bfh[j], acc[i][j], 0, 0, 0);
        acc[i][j] = __builtin_amdgcn_mfma_f32_16x16x32_bf16(afl[i], bfh[j], acc[i][j], 0, 0, 0);
        acc[i][j] = __builtin_amdgcn_mfma_f32_16x16x32_bf16(afh[i], bfl[j], acc[i][j], 0, 0, 0);
      }
    __syncthreads();
  }
#pragma unroll
  for (int j = 0; j < 4; ++j) {
    int col = n0 + wn * 64 + j * 16 + (lane & 15);
    float bias = b1f[col];
#pragma unroll
    for (int i = 0; i < 4; ++i)
#pragma unroll
      for (int rg = 0; rg < 4; ++rg) {
        int row = m0 + wm * 64 + i * 16 + (lane >> 4) * 4 + rg;
        pre[(size_t)row * HID + col] = acc[i][j][rg] + bias;
      }
  }
}

// ---------------------------------------------------------------------------
// K2: barrier-free persistent scan (unchanged protocol from round 3; only the
// o_hi/o_lo store addresses changed to the tile-ready A layout).
// ---------------------------------------------------------------------------
__global__ __launch_bounds__(512) void scan_kernel(
    const float* __restrict__ w1, const float* __restrict__ pre,
    unsigned long long* hbuf,
    ushort_t* __restrict__ o_hi, ushort_t* __restrict__ o_lo,
    float* __restrict__ h_last_out) {
  __shared__ float wLds[16384];      // 64 KiB swizzled wh slice
  __shared__ float hs[2][512];
  __shared__ float part[2][528];

  const int bp = blockIdx.x & 7;
  const int sg = blockIdx.x >> 3;
  const int b0 = bp * 2, b1 = b0 + 1;
  const int tid = threadIdx.x;

#pragma unroll
  for (int k = 0; k < 8; ++k) {
    int uid = k * 512 + tid;
    int r = uid >> 7, u = uid & 127;
    float4 v = *(const float4*)(w1 + (size_t)(sg * 32 + r) * 1024 + 512 + u * 4);
    int dst = r * 512 + (u >> 3) * 32 + (((u & 7) ^ (r & 7)) << 2);
    *(float4*)(&wLds[dst]) = v;
  }
  __syncthreads();

  const int i = tid & 31, s = tid >> 5;
  const int rowbase = i * 512 + s * 32;
  const int isw = i & 7;

  for (int t = 0; t < T_STEPS; ++t) {
    const int cur = t & 1, nxt = cur ^ 1;

    float pv = 0.f;
    if (tid < 64) {
      int bl = tid >> 5, ii = tid & 31;
      pv = pre[(size_t)(t * BATCH + b0 + bl) * HID + sg * 32 + ii];
    }

    unsigned long long* p0 = hbuf + ((size_t)cur * BATCH + b0) * HID + tid;
    unsigned long long* p1 = hbuf + ((size_t)cur * BATCH + b1) * HID + tid;
    unsigned long long e0 = __hip_atomic_load(p0, __ATOMIC_RELAXED, __HIP_MEMORY_SCOPE_AGENT);
    unsigned long long e1 = __hip_atomic_load(p1, __ATOMIC_RELAXED, __HIP_MEMORY_SCOPE_AGENT);
    int spins = 0;
    while ((unsigned)(e0 >> 32) != (unsigned)t || (unsigned)(e1 >> 32) != (unsigned)t) {
      __builtin_amdgcn_s_sleep(1);
      if ((unsigned)(e0 >> 32) != (unsigned)t)
        e0 = __hip_atomic_load(p0, __ATOMIC_RELAXED, __HIP_MEMORY_SCOPE_AGENT);
      if ((unsigned)(e1 >> 32) != (unsigned)t)
        e1 = __hip_atomic_load(p1, __ATOMIC_RELAXED, __HIP_MEMORY_SCOPE_AGENT);
      if (++spins > (1 << 20)) break;
    }
    hs[0][tid] = __uint_as_float((unsigned)e0);
    hs[1][tid] = __uint_as_float((unsigned)e1);
    __syncthreads();

    float a0 = 0.f, a1 = 0.f;
#pragma unroll
    for (int u = 0; u < 8; ++u) {
      float4 w = *(const float4*)(&wLds[rowbase + ((u ^ isw) << 2)]);
      float4 h0 = *(const float4*)(&hs[0][s * 32 + (u << 2)]);
      float4 h1 = *(const float4*)(&hs[1][s * 32 + (u << 2)]);
      a0 += w.x * h0.x + w.y * h0.y + w.z * h0.z + w.w * h0.w;
      a1 += w.x * h1.x + w.y * h1.y + w.z * h1.z + w.w * h1.w;
    }
    part[0][s * 33 + i] = a0;
    part[1][s * 33 + i] = a1;
    __syncthreads();

    if (tid < 64) {
      int bl = tid >> 5, ii = tid & 31;
      float ssum = 0.f;
#pragma unroll
      for (int ss = 0; ss < 16; ++ss) ssum += part[bl][ss * 33 + ii];
      ssum += pv;
      float hn = tanhf(ssum);
      int b = b0 + bl;
      unsigned long long ev = ((unsigned long long)(unsigned)(t + 1) << 32) |
                              (unsigned long long)__float_as_uint(hn);
      __hip_atomic_store(hbuf + ((size_t)nxt * BATCH + b) * HID + sg * 32 + ii, ev,
                         __ATOMIC_RELAXED, __HIP_MEMORY_SCOPE_AGENT);
      // tile-ready A-layout store: m-row -> (mt, r); col = sg*32+ii -> ks=sg
      int m = t * BATCH + b;
      int mt = m >> 7, r = m & 127;
      int kg = ii >> 3, e = ii & 7;
      size_t ao = ((size_t)(mt * 16 + sg) * 512 + unit_swz(r, kg)) * 8 + e;
      unsigned short hi_ = f2bf_rne(hn);
      o_hi[ao] = hi_;
      o_lo[ao] = f2bf_rne(hn - bf2f(hi_));
      if (t == T_STEPS - 1) h_last_out[(size_t)b * HID + sg * 32 + ii] = hn;
    }
  }
}

// ---------------------------------------------------------------------------
// K3 v2: decode GEMM, all operands pre-split tile-ready bf16.
// Staging = pure global_load_lds x16B (wave w stages image w: Ah/Al/Bh/Bl,
// 8 KiB each, linear). 48 MFMA per 2-barrier phase. Conflict-free unit swizzle.
// ---------------------------------------------------------------------------
__global__ __launch_bounds__(256, 3) void dec_gemm_v2(
    const ushort_t* __restrict__ ahi, const ushort_t* __restrict__ alo,
    const ushort_t* __restrict__ bhi, const ushort_t* __restrict__ blo,
    const float* __restrict__ dec_b, float* __restrict__ out) {
  __shared__ s8v SB[2048];   // [0,512)=Ah [512,1024)=Al [1024,1536)=Bh [1536,2048)=Bl
  const int bid = blockIdx.x;
  const int wg = (bid & 7) * 1000 + (bid >> 3);   // XCD-bijective (8000%8==0)
  const int nt = wg >> 5, mt = wg & 31;           // mt fastest: B reuse in L2
  const int tid = threadIdx.x, lane = tid & 63, wv = tid >> 6;
  const int wm = wv >> 1, wn = wv & 1;
  const int kgl = lane >> 4, lr = lane & 15;
  f4v acc[4][4] = {};

  for (int ks = 0; ks < KT_DEC; ++ks) {
    if (ks) __syncthreads();          // prev compute done before LDS overwrite
    {
      char* lb = (char*)SB + wv * 8192;
      const size_t aoff = (size_t)(mt * 16 + ks) * 8192;
      const size_t boff = (size_t)(nt * 16 + ks) * 8192;
      const char* gs = (wv == 0) ? (const char*)ahi + aoff
                     : (wv == 1) ? (const char*)alo + aoff
                     : (wv == 2) ? (const char*)bhi + boff
                                 : (const char*)blo + boff;
#pragma unroll
      for (int p = 0; p < 8; ++p)
        gload16(gs + p * 1024 + (size_t)lane * 16, lb + p * 1024);
    }
    __syncthreads();                  // vmcnt drain: tile ready
    s8v afh[4], afl[4], bfh[4], bfl[4];
#pragma unroll
    for (int f = 0; f < 4; ++f) {
      int rA = wm * 64 + f * 16 + lr;
      int uA = unit_swz(rA, kgl);
      afh[f] = SB[uA];        afl[f] = SB[512 + uA];
      int rB = wn * 64 + f * 16 + lr;
      int uB = unit_swz(rB, kgl);
      bfh[f] = SB[1024 + uB]; bfl[f] = SB[1536 + uB];
    }
#pragma unroll
    for (int i = 0; i < 4; ++i)
#pragma unroll
      for (int j = 0; j < 4; ++j) {
        acc[i][j] = __builtin_amdgcn_mfma_f32_16x16x32_bf16(afh[i], bfh[j], acc[i][j], 0, 0, 0);
        acc[i][j] = __builtin_amdgcn_mfma_f32_16x16x32_bf16(afl[i], bfh[j], acc[i][j], 0, 0, 0);
        acc[i][j] = __builtin_amdgcn_mfma_f32_16x16x32_bf16(afh[i], bfl[j], acc[i][j], 0, 0, 0);
      }
  }
  const int m0 = mt * 128, n0 = nt * 128;
#pragma unroll
  for (int j = 0; j < 4; ++j) {
    int col = n0 + wn * 64 + j * 16 + lr;
    float bias = dec_b[col];
#pragma unroll
    for (int i = 0; i < 4; ++i)
#pragma unroll
      for (int rg = 0; rg < 4; ++rg) {
        int row = m0 + wm * 64 + i * 16 + (lane >> 4) * 4 + rg;
        out[(size_t)row * VOCAB + col] = acc[i][j][rg] + bias;
      }
  }
}

// ---------------------------------------------------------------------------
// K3 fallback (ws too small for presplit): tile-ready A, on-the-fly-split B.
// ---------------------------------------------------------------------------
__global__ __launch_bounds__(256, 2) void dec_gemm_fb(
    const ushort_t* __restrict__ o_hi, const ushort_t* __restrict__ o_lo,
    const float* __restrict__ dec_w, const float* __restrict__ dec_b,
    float* __restrict__ out) {
  __shared__ s8v Ah[512], Al[512], Bh[512], Bl[512];
  const int mt = blockIdx.x, nt = blockIdx.y;
  const int tid = threadIdx.x;
  const int lane = tid & 63, wave = tid >> 6;
  const int wm = wave >> 1, wn = wave & 1;
  const int kgl = lane >> 4, lr = lane & 15;
  const int m0 = mt * 128, n0 = nt * 128;
  f4v acc[4][4] = {};

  for (int ks = 0; ks < KT_DEC; ++ks) {
    const int k0 = ks * 32;
#pragma unroll
    for (int c = 0; c < 2; ++c) {
      int idx = c * 256 + tid;
      // A: linear copy of pre-swizzled tile image
      size_t abase = (size_t)(mt * 16 + ks) * 4096 + (size_t)idx * 8;
      Ah[idx] = *(const s8v*)(o_hi + abase);
      Al[idx] = *(const s8v*)(o_lo + abase);
      // B: split on the fly
      int r = idx >> 2, kg = idx & 3;
      const float* bs = dec_w + (size_t)(n0 + r) * HID + k0 + kg * 8;
      float4 b0 = *(const float4*)bs;
      float4 b1v = *(const float4*)(bs + 4);
      float bv[8] = {b0.x, b0.y, b0.z, b0.w, b1v.x, b1v.y, b1v.z, b1v.w};
      s8v bh, bl;
#pragma unroll
      for (int j = 0; j < 8; ++j) {
        unsigned short h = f2bf_rne(bv[j]);
        bh[j] = (short)h;
        bl[j] = (short)f2bf_rne(bv[j] - bf2f(h));
      }
      int ub = unit_swz(r, kg);
      Bh[ub] = bh;  Bl[ub] = bl;
    }
    __syncthreads();
    s8v afh[4], afl[4], bfh[4], bfl[4];
#pragma unroll
    for (int f = 0; f < 4; ++f) {
      int rA = wm * 64 + f * 16 + lr;
      int uA = unit_swz(rA, kgl);
      afh[f] = Ah[uA];  afl[f] = Al[uA];
      int rB = wn * 64 + f * 16 + lr;
      int uB = unit_swz(rB, kgl);
      bfh[f] = Bh[uB];  bfl[f] = Bl[uB];
    }
#pragma unroll
    for (int i = 0; i < 4; ++i)
#pragma unroll
      for (int j = 0; j < 4; ++j) {
        acc[i][j] = __builtin_amdgcn_mfma_f32_16x16x32_bf16(afh[i], bfh[j], acc[i][j], 0, 0, 0);
        acc[i][j] = __builtin_amdgcn_mfma_f32_16x16x32_bf16(afl[i], bfh[j], acc[i][j], 0, 0, 0);
        acc[i][j] = __builtin_amdgcn_mfma_f32_16x16x32_bf16(afh[i], bfl[j], acc[i][j], 0, 0, 0);
      }
    __syncthreads();
  }
#pragma unroll
  for (int j = 0; j < 4; ++j) {
    int col = n0 + wn * 64 + j * 16 + lr;
    float bias = dec_b[col];
#pragma unroll
    for (int i = 0; i < 4; ++i)
#pragma unroll
      for (int rg = 0; rg < 4; ++rg) {
        int row = m0 + wm * 64 + i * 16 + (lane >> 4) * 4 + rg;
        out[(size_t)row * VOCAB + col] = acc[i][j][rg] + bias;
      }
  }
}

// ---------------------------------------------------------------------------
// Workspace layout (bytes):
//   [0,       128 KiB)   hbuf: u64[2][16][512] (tag|f32)  (zeroed each call)
//   [1 MiB,    9 MiB)    pre : 4096 x 512 f32
//   [16 MiB,  20 MiB)    o_hi: tile-ready A hi (32x16 tiles x 8 KiB)
//   [20 MiB,  24 MiB)    o_lo: tile-ready A lo
//   [24 MiB,  ~55 MiB)   bhi : tile-ready dec_w hi (250x16 tiles x 8 KiB)
//   [56 MiB,  ~87 MiB)   blo : tile-ready dec_w lo
// ---------------------------------------------------------------------------
extern "C" void kernel_launch(void* const* d_in, const int* in_sizes, int n_in,
                              void* d_out, int out_size, void* d_ws, size_t ws_size,
                              hipStream_t stream) {
  (void)in_sizes; (void)n_in; (void)out_size;
  const int*   tok   = (const int*)d_in[0];
  const float* emb   = (const float*)d_in[2];
  const float* w1    = (const float*)d_in[3];
  const float* b1    = (const float*)d_in[4];
  const float* dec_w = (const float*)d_in[5];
  const float* dec_b = (const float*)d_in[6];
  char* ws = (char*)d_ws;
  unsigned long long* hbuf = (unsigned long long*)(ws);
  float* pre  = (float*)(ws + (1u << 20));
  ushort_t* o_hi = (ushort_t*)(ws + 16u * (1u << 20));
  ushort_t* o_lo = (ushort_t*)(ws + 20u * (1u << 20));
  ushort_t* bhi  = (ushort_t*)(ws + 24u * (1u << 20));
  ushort_t* blo  = (ushort_t*)(ws + 56u * (1u << 20));
  float* out = (float*)d_out;

  const int big = (ws_size >= (size_t)92 * 1024 * 1024) ? 1 : 0;

  hipMemsetAsync(ws, 0, 131072, stream);   // tag=0, h0=0
  head_kernel<<<dim3(4128), dim3(256), 0, stream>>>(
      tok, emb, w1, b1, pre, dec_w, bhi, blo, big);
  scan_kernel<<<dim3(128), dim3(512), 0, stream>>>(
      w1, pre, hbuf, o_hi, o_lo, out + (size_t)M_TOT * VOCAB);
  if (big)
    dec_gemm_v2<<<dim3(8000), dim3(256), 0, stream>>>(o_hi, o_lo, bhi, blo, dec_b, out);
  else
    dec_gemm_fb<<<dim3(32, 250), dim3(256), 0, stream>>>(o_hi, o_lo, dec_w, dec_b, out);
}